// Round 3
// baseline (31375.760 us; speedup 1.0000x reference)
//
#include <hip/hip_runtime.h>
#include <hip/hip_bf16.h>
#include <math.h>

// GLA cross-attention — FULL NAIVE DIAGNOSTIC REWRITE (round 3).
// Rounds 1 & 2 failed with bit-identical absmax (6.2866e-3) despite different
// attention/layout implementations => bug is in shared code (tiled gemm / rms)
// or in the semantic model. This round shares ZERO lines with rounds 1-2:
// every stage is a maximally-simple, obviously-correct kernel. Slow (~20 ms)
// by design; this is a bisection probe, not an optimization step.
//
// ws layout (float offsets), 53,477,376 floats total (213.9 MB, same as r2):
//   q_lat    [0         .. 1,048,576)
//   q_up     [1,048,576 .. 7,340,032)     dead after extract
//   attn_out [0         .. 4,194,304)     reuses region A after q_up is dead
//   qbuf     [7,340,032 .. 11,534,336)
//   ckv      [11,534,336.. 19,922,944)
//   kvg      [19,922,944.. 53,477,376)    4 groups x 8192 x 1024

// C[M,N] = A[M,K] @ B[K,N]; one thread per C element. Coalesced in j (B rows
// broadcast-friendly in A). No LDS, no tiling, no tricks.
__global__ __launch_bounds__(256) void gemm_naive(const float* __restrict__ A,
        const float* __restrict__ B, float* __restrict__ C,
        long M, long N, long K, long lda, long ldb, long ldc)
{
    long idx = (long)blockIdx.x * 256 + threadIdx.x;
    if (idx >= M * N) return;
    long i = idx / N, j = idx % N;
    const float* ap = A + i * lda;
    const float* bp = B + j;
    float s = 0.f;
    for (long k = 0; k < K; ++k)
        s += ap[k] * bp[k * ldb];
    C[i * ldc + j] = s;
}

// rmsnorm, one THREAD per (row, group). n = rows*groups; row block at
// x + r*rowstride + g*cols, weight at w + g*cols, normalized over `cols`.
__global__ __launch_bounds__(256) void rms_naive(float* __restrict__ x,
        const float* __restrict__ w, long n, long cols, long rowstride, long groups)
{
    long t = (long)blockIdx.x * 256 + threadIdx.x;
    if (t >= n) return;
    long r = t / groups, g = t % groups;
    float* p = x + r * rowstride + g * cols;
    const float* wp = w + g * cols;
    float ss = 0.f;
    for (long c = 0; c < cols; ++c) ss += p[c] * p[c];
    float inv = rsqrtf(ss / (float)cols + 1e-6f);
    for (long c = 0; c < cols; ++c) p[c] = p[c] * inv * wp[c];
}

// q_up (2048 x 3072, 192 per head) -> qbuf (2048 x 2048, first 128 per head)
__global__ __launch_bounds__(256) void extract_naive(const float* __restrict__ src,
        float* __restrict__ dst)
{
    int t = blockIdx.x * 256 + threadIdx.x;     // 0 .. 4,194,303
    int r = t >> 11;
    int c = t & 2047;
    int h = c >> 7, d = c & 127;
    dst[(size_t)r * 2048 + c] = src[(size_t)r * 3072 + h * 192 + d];
}

// Exact two-pass softmax attention. One wave per (q, h, b). Lane owns dims
// d and d+64. Pass 1: row max. Pass 2: denominator + weighted V accumulate.
// kvg group layout: kvg + g*8388608 rows (b*4096+s)*1024, head slot p=h&3:
// K at p*256 + d, V at p*256 + 128 + d.
__global__ __launch_bounds__(64) void attn_naive(const float* __restrict__ Q,
        const float* __restrict__ KV, float* __restrict__ O)
{
    const int qi = blockIdx.x, h = blockIdx.y, b = blockIdx.z;
    const int lane = threadIdx.x;
    const float scale = 0.08838834764831845f;   // 1/sqrt(128)
    const int g = h >> 2, p = h & 3;

    const float* qp = Q + (size_t)(b * 1024 + qi) * 2048 + h * 128;
    const float* kv = KV + (size_t)g * 8388608ull + (size_t)b * 4096 * 1024 + p * 256;
    const float q0 = qp[lane], q1 = qp[lane + 64];

    float m = -1e30f;
    for (int s = 0; s < 4096; ++s) {
        const float* kr = kv + (size_t)s * 1024;
        float part = q0 * kr[lane] + q1 * kr[lane + 64];
        #pragma unroll
        for (int msk = 32; msk; msk >>= 1) part += __shfl_xor(part, msk);
        m = fmaxf(m, part * scale);
    }
    float l = 0.f, a0 = 0.f, a1 = 0.f;
    for (int s = 0; s < 4096; ++s) {
        const float* kr = kv + (size_t)s * 1024;
        float part = q0 * kr[lane] + q1 * kr[lane + 64];
        #pragma unroll
        for (int msk = 32; msk; msk >>= 1) part += __shfl_xor(part, msk);
        float wgt = __expf(part * scale - m);
        l += wgt;
        a0 += wgt * kr[128 + lane];
        a1 += wgt * kr[128 + lane + 64];
    }
    float* op = O + (size_t)(b * 1024 + qi) * 2048 + h * 128;
    op[lane]      = a0 / l;
    op[lane + 64] = a1 / l;
}

extern "C" void kernel_launch(void* const* d_in, const int* in_sizes, int n_in,
                              void* d_out, int out_size, void* d_ws, size_t ws_size,
                              hipStream_t stream)
{
    (void)in_sizes; (void)n_in; (void)out_size; (void)ws_size;
    const float* x_q       = (const float*)d_in[0];
    const float* x_kv      = (const float*)d_in[1];
    const float* W_dQ      = (const float*)d_in[2];
    const float* q_norm_w  = (const float*)d_in[3];
    const float* W_uQ      = (const float*)d_in[4];
    const float* W_dKV     = (const float*)d_in[5];
    const float* kv_norm_w = (const float*)d_in[6];
    const float* W_ukv     = (const float*)d_in[7];
    const float* W_o       = (const float*)d_in[8];
    float* out = (float*)d_out;

    float* ws       = (float*)d_ws;
    float* q_lat    = ws;
    float* q_up     = ws + 1048576ull;
    float* attn_out = ws;                      // region A reuse, q_up dead by then
    float* qbuf     = ws + 7340032ull;
    float* ckv      = ws + 11534336ull;
    float* kvg      = ws + 19922944ull;

    // 1) q_lat = x_q @ W_dQ                      (2048 x 512, K=2048)
    gemm_naive<<<4096, 256, 0, stream>>>(x_q, W_dQ, q_lat, 2048, 512, 2048, 2048, 512, 512);
    // 2) rmsnorm(q_lat) over 512, weight q_norm_w
    rms_naive<<<8, 256, 0, stream>>>(q_lat, q_norm_w, 2048, 512, 512, 1);
    // 3) q_up = q_lat @ W_uQ                     (2048 x 3072, K=512)
    gemm_naive<<<24576, 256, 0, stream>>>(q_lat, W_uQ, q_up, 2048, 3072, 512, 512, 3072, 3072);
    // 3b) per-head [:128] slice
    extract_naive<<<16384, 256, 0, stream>>>(q_up, qbuf);
    // 4) ckv = x_kv @ W_dKV[:, :1024]            (8192 x 1024, K=2048, ldb=1088)
    gemm_naive<<<32768, 256, 0, stream>>>(x_kv, W_dKV, ckv, 8192, 1024, 2048, 2048, 1088, 1024);
    // 5) grouped rmsnorm over 256 per (row, g)
    rms_naive<<<128, 256, 0, stream>>>(ckv, kv_norm_w, 32768, 256, 1024, 4);
    // 6) kv up-projection per group               (8192 x 1024, K=256) x4
    for (int g = 0; g < 4; ++g)
        gemm_naive<<<32768, 256, 0, stream>>>(ckv + g * 256, W_ukv + (size_t)g * 262144,
                                              kvg + (size_t)g * 8388608ull,
                                              8192, 1024, 256, 1024, 1024, 1024);
    // 7) exact two-pass attention
    attn_naive<<<dim3(1024, 16, 2), 64, 0, stream>>>(qbuf, kvg, attn_out);
    // 8) out = attn_out @ W_o                     (2048 x 2048, K=2048)
    gemm_naive<<<16384, 256, 0, stream>>>(attn_out, W_o, out, 2048, 2048, 2048, 2048, 2048, 2048);
}

// Round 4
// 3538.484 us; speedup vs baseline: 8.8670x; 8.8670x over previous
//
#include <hip/hip_runtime.h>
#include <hip/hip_bf16.h>
#include <math.h>

// GLA cross-attention — round 4: r3-verified pipeline with (a) fast attention
// (r2's kernel, exonerated by r1/r2 identical-error forensics) and (b) a NEW
// fp32 tiled GEMM (64x64 tile, 4x4/thread). gemm128 from r1/r2 is retired.
// rms / extract / ws layout are byte-identical to the PASSING round 3.
//
// ws layout (float offsets), 53,477,376 floats (213.9 MB):
//   q_lat    [0 .. 1,048,576)
//   q_up     [1,048,576 .. 7,340,032)     dead after extract
//   attn_out [0 .. 4,194,304)             reuses region A after q_up dead
//   qbuf     [7,340,032 .. 11,534,336)
//   ckv      [11,534,336 .. 19,922,944)
//   kvg      [19,922,944 .. 53,477,376)   4 groups x 8192 x 1024

// ---------- fp32 tiled GEMM: C[M,N] = A[M,K] @ B[K,N]
// 64x64 block tile, 256 threads, 4x4 per thread, KT=16.
// Requires: M,N % 64 == 0, K % 16 == 0, ldb/ldc % 4 == 0 (float4 alignment).
__global__ __launch_bounds__(256) void tgemm(const float* __restrict__ A,
        const float* __restrict__ B, float* __restrict__ C,
        int M, int N, int K, int lda, int ldb, int ldc)
{
    __shared__ __align__(16) float As[64][17];   // [m][k], +1 pad
    __shared__ __align__(16) float Bs[16][68];   // [k][n], +4 pad (16B-aligned rows)
    const int tid = threadIdx.x;
    const int tn = tid & 15;          // n sub-tile: cols 4*tn..+3
    const int tm = tid >> 4;          // m sub-tile: rows 4*tm..+3
    const int m0 = blockIdx.y * 64;
    const int n0 = blockIdx.x * 64;

    const int ar = tid >> 2, ac = (tid & 3) * 4;     // A: 64 rows x 4 float4
    const int br = tid >> 4, bc = (tid & 15) * 4;    // B: 16 rows x 16 float4

    float acc[4][4];
    #pragma unroll
    for (int i = 0; i < 4; ++i)
        #pragma unroll
        for (int j = 0; j < 4; ++j) acc[i][j] = 0.f;

    for (int k0 = 0; k0 < K; k0 += 16) {
        float4 a4 = *(const float4*)&A[(size_t)(m0 + ar) * lda + k0 + ac];
        As[ar][ac + 0] = a4.x; As[ar][ac + 1] = a4.y;
        As[ar][ac + 2] = a4.z; As[ar][ac + 3] = a4.w;
        *(float4*)&Bs[br][bc] = *(const float4*)&B[(size_t)(k0 + br) * ldb + n0 + bc];
        __syncthreads();
        #pragma unroll
        for (int kk = 0; kk < 16; ++kk) {
            float a0 = As[4 * tm + 0][kk];
            float a1 = As[4 * tm + 1][kk];
            float a2 = As[4 * tm + 2][kk];
            float a3 = As[4 * tm + 3][kk];
            float4 b = *(const float4*)&Bs[kk][4 * tn];
            float bv[4] = {b.x, b.y, b.z, b.w};
            #pragma unroll
            for (int j = 0; j < 4; ++j) {
                acc[0][j] += a0 * bv[j];
                acc[1][j] += a1 * bv[j];
                acc[2][j] += a2 * bv[j];
                acc[3][j] += a3 * bv[j];
            }
        }
        __syncthreads();
    }
    #pragma unroll
    for (int i = 0; i < 4; ++i) {
        float* cp = C + (size_t)(m0 + 4 * tm + i) * ldc + n0 + 4 * tn;
        *(float4*)cp = make_float4(acc[i][0], acc[i][1], acc[i][2], acc[i][3]);
    }
}

// ---------- rmsnorm (VERIFIED r3): one thread per (row, group)
__global__ __launch_bounds__(256) void rms_naive(float* __restrict__ x,
        const float* __restrict__ w, long n, long cols, long rowstride, long groups)
{
    long t = (long)blockIdx.x * 256 + threadIdx.x;
    if (t >= n) return;
    long r = t / groups, g = t % groups;
    float* p = x + r * rowstride + g * cols;
    const float* wp = w + g * cols;
    float ss = 0.f;
    for (long c = 0; c < cols; ++c) ss += p[c] * p[c];
    float inv = rsqrtf(ss / (float)cols + 1e-6f);
    for (long c = 0; c < cols; ++c) p[c] = p[c] * inv * wp[c];
}

// ---------- q slice (VERIFIED r3)
__global__ __launch_bounds__(256) void extract_naive(const float* __restrict__ src,
        float* __restrict__ dst)
{
    int t = blockIdx.x * 256 + threadIdx.x;     // 0 .. 4,194,303
    int r = t >> 11;
    int c = t & 2047;
    int h = c >> 7, d = c & 127;
    dst[(size_t)r * 2048 + c] = src[(size_t)r * 3072 + h * 192 + d];
}

// ---------- flash attention (r2 kernel, exonerated). grid (QL/32, H, B), 256 thr.
// Q: (b*1024+q)*2048 + h*128 + d.  KV group g: kvg + g*8388608, row (b*4096+s)*1024,
// head slot p=h&3: K at p*256+d, V at p*256+128+d.
__global__ __launch_bounds__(256) void attn_kernel(const float* __restrict__ Qm,
        const float* __restrict__ KVg, float* __restrict__ Om)
{
    __shared__ __align__(16) float Qs [32][132];
    __shared__ __align__(16) float Ks [32][132];
    __shared__ __align__(16) float Vls[32][132];
    __shared__ float Ps[32][36];
    __shared__ float mrow[32], lrow[32], arow[32];

    const int q0 = blockIdx.x * 32;
    const int h  = blockIdx.y;
    const int b  = blockIdx.z;
    const int g  = h >> 2;
    const int p  = h & 3;
    const int tid = threadIdx.x;
    const float scale = 0.08838834764831845f;   // 1/sqrt(128)

    const float* qbase  = Qm + (size_t)(b * 1024 + q0) * 2048 + h * 128;
    const float* kvbase = KVg + (size_t)g * 8388608ull + (size_t)b * 4096 * 1024 + p * 256;

    #pragma unroll
    for (int i = 0; i < 4; ++i) {               // Q tile 32x128, loaded once
        int idx4 = tid + 256 * i;
        int r = idx4 >> 5, c4 = idx4 & 31;
        *(float4*)&Qs[r][c4 * 4] = *(const float4*)(qbase + (size_t)r * 2048 + c4 * 4);
    }
    if (tid < 32) { mrow[tid] = -INFINITY; lrow[tid] = 0.f; }

    const int ty = tid >> 4;           // PV mapping: q rows 2*ty, 2*ty+1
    const int tx = tid & 15;           //             d cols 8*tx..+7
    const int r0 = 2 * ty, r1 = 2 * ty + 1;
    const int dc = 8 * tx;
    float o0[8], o1[8];
    #pragma unroll
    for (int j = 0; j < 8; ++j) { o0[j] = 0.f; o1[j] = 0.f; }

    const int qrow = tid >> 3;         // QK mapping: 1 q row, 4 s cols
    const int sx   = tid & 7;

    for (int s0 = 0; s0 < 4096; s0 += 32) {
        __syncthreads();               // prev tile's K/V/P reads done
        #pragma unroll
        for (int i = 0; i < 4; ++i) {  // K,V tiles 32x128
            int idx4 = tid + 256 * i;
            int r = idx4 >> 5, c4 = idx4 & 31;
            const float* kp = kvbase + (size_t)(s0 + r) * 1024 + c4 * 4;
            *(float4*)&Ks [r][c4 * 4] = *(const float4*)kp;
            *(float4*)&Vls[r][c4 * 4] = *(const float4*)(kp + 128);
        }
        __syncthreads();
        float acc[4] = {0.f, 0.f, 0.f, 0.f};
        for (int d4 = 0; d4 < 32; ++d4) {
            float4 qv = *(const float4*)&Qs[qrow][d4 * 4];
            #pragma unroll
            for (int j = 0; j < 4; ++j) {
                float4 kv = *(const float4*)&Ks[4 * sx + j][d4 * 4];
                acc[j] += qv.x * kv.x + qv.y * kv.y + qv.z * kv.z + qv.w * kv.w;
            }
        }
        #pragma unroll
        for (int j = 0; j < 4; ++j) Ps[qrow][4 * sx + j] = acc[j] * scale;
        __syncthreads();
        if (tid < 32) {                // online softmax: one thread per q row
            const int r = tid;
            float tm = -INFINITY;
            for (int s = 0; s < 32; ++s) tm = fmaxf(tm, Ps[r][s]);
            float mn = fmaxf(mrow[r], tm);
            float a  = __expf(mrow[r] - mn);
            float rs = 0.f;
            for (int s = 0; s < 32; ++s) { float e = __expf(Ps[r][s] - mn); Ps[r][s] = e; rs += e; }
            lrow[r] = lrow[r] * a + rs;
            mrow[r] = mn;
            arow[r] = a;
        }
        __syncthreads();
        float a0 = arow[r0], a1 = arow[r1];
        #pragma unroll
        for (int j = 0; j < 8; ++j) { o0[j] *= a0; o1[j] *= a1; }
        for (int s = 0; s < 32; ++s) {
            float p0 = Ps[r0][s], p1 = Ps[r1][s];
            float4 v0 = *(const float4*)&Vls[s][dc];
            float4 v1 = *(const float4*)&Vls[s][dc + 4];
            float vv[8] = {v0.x, v0.y, v0.z, v0.w, v1.x, v1.y, v1.z, v1.w};
            #pragma unroll
            for (int j = 0; j < 8; ++j) { o0[j] += p0 * vv[j]; o1[j] += p1 * vv[j]; }
        }
    }
    float inv0 = 1.f / lrow[r0];
    float inv1 = 1.f / lrow[r1];
    float* ob0 = Om + (size_t)(b * 1024 + q0 + r0) * 2048 + h * 128 + dc;
    float* ob1 = Om + (size_t)(b * 1024 + q0 + r1) * 2048 + h * 128 + dc;
    *(float4*)ob0       = make_float4(o0[0]*inv0, o0[1]*inv0, o0[2]*inv0, o0[3]*inv0);
    *(float4*)(ob0 + 4) = make_float4(o0[4]*inv0, o0[5]*inv0, o0[6]*inv0, o0[7]*inv0);
    *(float4*)ob1       = make_float4(o1[0]*inv1, o1[1]*inv1, o1[2]*inv1, o1[3]*inv1);
    *(float4*)(ob1 + 4) = make_float4(o1[4]*inv1, o1[5]*inv1, o1[6]*inv1, o1[7]*inv1);
}

extern "C" void kernel_launch(void* const* d_in, const int* in_sizes, int n_in,
                              void* d_out, int out_size, void* d_ws, size_t ws_size,
                              hipStream_t stream)
{
    (void)in_sizes; (void)n_in; (void)out_size; (void)ws_size;
    const float* x_q       = (const float*)d_in[0];
    const float* x_kv      = (const float*)d_in[1];
    const float* W_dQ      = (const float*)d_in[2];
    const float* q_norm_w  = (const float*)d_in[3];
    const float* W_uQ      = (const float*)d_in[4];
    const float* W_dKV     = (const float*)d_in[5];
    const float* kv_norm_w = (const float*)d_in[6];
    const float* W_ukv     = (const float*)d_in[7];
    const float* W_o       = (const float*)d_in[8];
    float* out = (float*)d_out;

    float* ws       = (float*)d_ws;
    float* q_lat    = ws;
    float* q_up     = ws + 1048576ull;
    float* attn_out = ws;                      // region A reuse, q_up dead by then
    float* qbuf     = ws + 7340032ull;
    float* ckv      = ws + 11534336ull;
    float* kvg      = ws + 19922944ull;

    // 1) q_lat = x_q @ W_dQ                      (2048 x 512, K=2048)
    tgemm<<<dim3(8, 32), 256, 0, stream>>>(x_q, W_dQ, q_lat, 2048, 512, 2048, 2048, 512, 512);
    // 2) rmsnorm(q_lat) over 512
    rms_naive<<<8, 256, 0, stream>>>(q_lat, q_norm_w, 2048, 512, 512, 1);
    // 3) q_up = q_lat @ W_uQ                     (2048 x 3072, K=512)
    tgemm<<<dim3(48, 32), 256, 0, stream>>>(q_lat, W_uQ, q_up, 2048, 3072, 512, 512, 3072, 3072);
    // 3b) per-head [:128] slice
    extract_naive<<<16384, 256, 0, stream>>>(q_up, qbuf);
    // 4) ckv = x_kv @ W_dKV[:, :1024]            (8192 x 1024, K=2048, ldb=1088)
    tgemm<<<dim3(16, 128), 256, 0, stream>>>(x_kv, W_dKV, ckv, 8192, 1024, 2048, 2048, 1088, 1024);
    // 5) grouped rmsnorm over 256 per (row, g)
    rms_naive<<<128, 256, 0, stream>>>(ckv, kv_norm_w, 32768, 256, 1024, 4);
    // 6) kv up-projection per group               (8192 x 1024, K=256) x4
    for (int g = 0; g < 4; ++g)
        tgemm<<<dim3(16, 128), 256, 0, stream>>>(ckv + g * 256, W_ukv + (size_t)g * 262144,
                                                 kvg + (size_t)g * 8388608ull,
                                                 8192, 1024, 256, 1024, 1024, 1024);
    // 7) flash attention
    attn_kernel<<<dim3(32, 16, 2), 256, 0, stream>>>(qbuf, kvg, attn_out);
    // 8) out = attn_out @ W_o                     (2048 x 2048, K=2048)
    tgemm<<<dim3(32, 32), 256, 0, stream>>>(attn_out, W_o, out, 2048, 2048, 2048, 2048, 2048, 2048);
}

// Round 5
// 1736.658 us; speedup vs baseline: 18.0667x; 2.0375x over previous
//
#include <hip/hip_runtime.h>
#include <hip/hip_bf16.h>
#include <math.h>

// GLA cross-attention — round 5: MFMA bf16 flash attention; verified fp32 tgemm
// for all GEMM stages (stage 6 gains a bf16-output epilogue).
// Pipeline: tgemm(q_lat) -> rms -> tgemm(q_up) -> extract_q_bf16(+fold 1/sqrt(128))
//        -> tgemm(ckv) -> rms -> 4x tgemm(kv up, bf16 out) -> transpose_v
//        -> attn_mfma -> tgemm(W_o)
// ws (float units, 172 MB total):
//   q_lat   [0 .. 1,048,576)
//   q_up    [1,048,576 .. 7,340,032)      dead after extract
//   attn_out[0 .. 4,194,304)              reuses region A
//   ckv     [7,340,032 .. 15,728,640)
//   kvgb    [15,728,640 .. 32,505,856)    bf16: 4 groups x 8192 x 1024 ushorts
//   qb      [32,505,856 .. 34,603,008)    bf16: 2048 x 2048 ushorts (pre-scaled)
//   Vt      [34,603,008 .. 42,991,616)    bf16: [b,h][128 d][4096 s]

typedef __attribute__((ext_vector_type(8))) short short8;
typedef __attribute__((ext_vector_type(4))) float f32x4;

__device__ __forceinline__ ushort f2bf(float x) {
    __hip_bfloat16 h = __float2bfloat16(x);
    return *reinterpret_cast<ushort*>(&h);
}

// ---------- fp32 tiled GEMM (VERIFIED r4) + optional bf16-output epilogue.
// 64x64 tile, 256 threads, 4x4/thread, KT=16. obf16: C is ushort*, ldc in ushorts.
__global__ __launch_bounds__(256) void tgemm(const float* __restrict__ A,
        const float* __restrict__ B, float* __restrict__ C,
        int M, int N, int K, int lda, int ldb, int ldc, int obf16)
{
    __shared__ __align__(16) float As[64][17];
    __shared__ __align__(16) float Bs[16][68];
    const int tid = threadIdx.x;
    const int tn = tid & 15;
    const int tm = tid >> 4;
    const int m0 = blockIdx.y * 64;
    const int n0 = blockIdx.x * 64;

    const int ar = tid >> 2, ac = (tid & 3) * 4;
    const int br = tid >> 4, bc = (tid & 15) * 4;

    float acc[4][4];
    #pragma unroll
    for (int i = 0; i < 4; ++i)
        #pragma unroll
        for (int j = 0; j < 4; ++j) acc[i][j] = 0.f;

    for (int k0 = 0; k0 < K; k0 += 16) {
        float4 a4 = *(const float4*)&A[(size_t)(m0 + ar) * lda + k0 + ac];
        As[ar][ac + 0] = a4.x; As[ar][ac + 1] = a4.y;
        As[ar][ac + 2] = a4.z; As[ar][ac + 3] = a4.w;
        *(float4*)&Bs[br][bc] = *(const float4*)&B[(size_t)(k0 + br) * ldb + n0 + bc];
        __syncthreads();
        #pragma unroll
        for (int kk = 0; kk < 16; ++kk) {
            float a0 = As[4 * tm + 0][kk];
            float a1 = As[4 * tm + 1][kk];
            float a2 = As[4 * tm + 2][kk];
            float a3 = As[4 * tm + 3][kk];
            float4 b = *(const float4*)&Bs[kk][4 * tn];
            float bv[4] = {b.x, b.y, b.z, b.w};
            #pragma unroll
            for (int j = 0; j < 4; ++j) {
                acc[0][j] += a0 * bv[j];
                acc[1][j] += a1 * bv[j];
                acc[2][j] += a2 * bv[j];
                acc[3][j] += a3 * bv[j];
            }
        }
        __syncthreads();
    }
    if (!obf16) {
        #pragma unroll
        for (int i = 0; i < 4; ++i) {
            float* cp = C + (size_t)(m0 + 4 * tm + i) * ldc + n0 + 4 * tn;
            *(float4*)cp = make_float4(acc[i][0], acc[i][1], acc[i][2], acc[i][3]);
        }
    } else {
        ushort* Cu = (ushort*)C;
        #pragma unroll
        for (int i = 0; i < 4; ++i) {
            ushort* cp = Cu + (size_t)(m0 + 4 * tm + i) * ldc + n0 + 4 * tn;
            ushort4 u;
            u.x = f2bf(acc[i][0]); u.y = f2bf(acc[i][1]);
            u.z = f2bf(acc[i][2]); u.w = f2bf(acc[i][3]);
            *(ushort4*)cp = u;
        }
    }
}

// ---------- rmsnorm (VERIFIED r3)
__global__ __launch_bounds__(256) void rms_naive(float* __restrict__ x,
        const float* __restrict__ w, long n, long cols, long rowstride, long groups)
{
    long t = (long)blockIdx.x * 256 + threadIdx.x;
    if (t >= n) return;
    long r = t / groups, g = t % groups;
    float* p = x + r * rowstride + g * cols;
    const float* wp = w + g * cols;
    float ss = 0.f;
    for (long c = 0; c < cols; ++c) ss += p[c] * p[c];
    float inv = rsqrtf(ss / (float)cols + 1e-6f);
    for (long c = 0; c < cols; ++c) p[c] = p[c] * inv * wp[c];
}

// ---------- q slice -> bf16, softmax scale folded in
__global__ __launch_bounds__(256) void extract_q_bf16(const float* __restrict__ src,
        ushort* __restrict__ dst)
{
    int t = blockIdx.x * 256 + threadIdx.x;     // 4,194,304 total
    int r = t >> 11, c = t & 2047;
    int h = c >> 7, d = c & 127;
    float v = src[(size_t)r * 3072 + h * 192 + d] * 0.08838834764831845f;
    dst[(size_t)r * 2048 + c] = f2bf(v);
}

// ---------- V transpose: kvgb V-halves -> Vt[b,h][d=128][s=4096] bf16
__global__ __launch_bounds__(256) void transpose_v(const ushort* __restrict__ KVb,
                                                   ushort* __restrict__ Vt)
{
    __shared__ ushort tile[64][66];
    const int s0 = blockIdx.x * 64;
    const int d0 = blockIdx.y * 64;
    const int bh = blockIdx.z;                  // b*16+h
    const int b = bh >> 4, h = bh & 15, g = h >> 2, p = h & 3;
    const int t = threadIdx.x;
    const ushort* src = KVb + (size_t)g * 8388608ull + (size_t)(b * 4096) * 1024 + p * 256 + 128;
    {
        int sl = t >> 4, c4 = t & 15;
        #pragma unroll
        for (int i = 0; i < 4; ++i) {
            int s = sl + 16 * i;
            ushort4 v = *(const ushort4*)(src + (size_t)(s0 + s) * 1024 + d0 + c4 * 4);
            tile[s][c4 * 4 + 0] = v.x; tile[s][c4 * 4 + 1] = v.y;
            tile[s][c4 * 4 + 2] = v.z; tile[s][c4 * 4 + 3] = v.w;
        }
    }
    __syncthreads();
    {
        int dl = t >> 4, s4 = t & 15;
        ushort* dst = Vt + (size_t)(b * 16 + h) * 128 * 4096;
        #pragma unroll
        for (int i = 0; i < 4; ++i) {
            int d = dl + 16 * i;
            ushort4 v;
            v.x = tile[s4 * 4 + 0][d]; v.y = tile[s4 * 4 + 1][d];
            v.z = tile[s4 * 4 + 2][d]; v.w = tile[s4 * 4 + 3][d];
            *(ushort4*)(dst + (size_t)(d0 + d) * 4096 + s0 + s4 * 4) = v;
        }
    }
}

// ---------- MFMA bf16 flash attention. grid (16, 16, 2), 256 thr = 4 waves.
// Block: 64 q rows for (b,h). Wave w: q rows w*16..+15 (A-frag m=lane&15).
// Qb pre-scaled bf16 [row][2048]; K from kvgb [g][(b*4096+s)*1024 + p*256 + d];
// V from Vt [b,h][d][4096]. Out fp32 attn_out [row][2048].
__global__ __launch_bounds__(256) void attn_mfma(const ushort* __restrict__ Qb,
        const ushort* __restrict__ KVb, const ushort* __restrict__ Vt,
        float* __restrict__ Om)
{
    __shared__ ushort Ks[64][136];     // [s][k] pad 8 (272B rows: 16B-aligned, 4-bank skew)
    __shared__ ushort VsT[128][72];    // [d][s] pad 8
    __shared__ ushort Ps[4][16][72];   // per-wave P [q16][s64] pad 8

    const int q0 = blockIdx.x * 64;
    const int h = blockIdx.y, b = blockIdx.z;
    const int g = h >> 2, p = h & 3;
    const int tid = threadIdx.x;
    const int w = tid >> 6, lane = tid & 63;
    const int quad = lane >> 4, l16 = lane & 15;

    const ushort* qg = Qb + (size_t)(b * 1024 + q0) * 2048 + h * 128;
    const ushort* kg = KVb + (size_t)g * 8388608ull + (size_t)(b * 4096) * 1024 + p * 256;
    const ushort* vg = Vt + (size_t)(b * 16 + h) * 128 * 4096;

    // stage Q through Ks, pull A-frags into registers
    {
        int r = tid >> 4, c8 = tid & 15;
        #pragma unroll
        for (int i = 0; i < 4; ++i)
            *(uint4*)&Ks[r + 16 * i][c8 * 8] =
                *(const uint4*)(qg + (size_t)(r + 16 * i) * 2048 + c8 * 8);
    }
    __syncthreads();
    short8 qf[4];
    {
        int qr = w * 16 + l16;
        #pragma unroll
        for (int kc = 0; kc < 4; ++kc)
            qf[kc] = *(const short8*)&Ks[qr][kc * 32 + quad * 8];
    }

    f32x4 accO[8];
    float m_i[4], l_i[4];
    #pragma unroll
    for (int dt = 0; dt < 8; ++dt) accO[dt] = (f32x4){0.f, 0.f, 0.f, 0.f};
    #pragma unroll
    for (int r = 0; r < 4; ++r) { m_i[r] = -INFINITY; l_i[r] = 0.f; }

    for (int s0 = 0; s0 < 4096; s0 += 64) {
        __syncthreads();               // prior tile's frag reads (and Q frag pull) done
        {
            int r = tid >> 4, c8 = tid & 15;
            #pragma unroll
            for (int i = 0; i < 4; ++i)
                *(uint4*)&Ks[r + 16 * i][c8 * 8] =
                    *(const uint4*)(kg + (size_t)(s0 + r + 16 * i) * 1024 + c8 * 8);
            int d = tid >> 3, s8 = tid & 7;
            #pragma unroll
            for (int i = 0; i < 4; ++i)
                *(uint4*)&VsT[d + 32 * i][s8 * 8] =
                    *(const uint4*)(vg + (size_t)(d + 32 * i) * 4096 + s0 + s8 * 8);
        }
        __syncthreads();
        // S = Q K^T  (C layout: row q = quad*4+reg, col s = st*16 + l16)
        f32x4 accS[4];
        #pragma unroll
        for (int st = 0; st < 4; ++st) accS[st] = (f32x4){0.f, 0.f, 0.f, 0.f};
        #pragma unroll
        for (int kc = 0; kc < 4; ++kc) {
            #pragma unroll
            for (int st = 0; st < 4; ++st) {
                short8 kf = *(const short8*)&Ks[st * 16 + l16][kc * 32 + quad * 8];
                accS[st] = __builtin_amdgcn_mfma_f32_16x16x32_bf16(qf[kc], kf, accS[st], 0, 0, 0);
            }
        }
        // online softmax per owned q row (quad*4+r), state replicated over 16 s-lanes
        #pragma unroll
        for (int r = 0; r < 4; ++r) {
            float tm = fmaxf(fmaxf(accS[0][r], accS[1][r]), fmaxf(accS[2][r], accS[3][r]));
            #pragma unroll
            for (int msk = 1; msk < 16; msk <<= 1) tm = fmaxf(tm, __shfl_xor(tm, msk));
            float mn = fmaxf(m_i[r], tm);
            float alpha = __expf(m_i[r] - mn);
            float rs = 0.f;
            #pragma unroll
            for (int st = 0; st < 4; ++st) {
                float e = __expf(accS[st][r] - mn);
                rs += e;
                Ps[w][quad * 4 + r][st * 16 + l16] = f2bf(e);
            }
            #pragma unroll
            for (int msk = 1; msk < 16; msk <<= 1) rs += __shfl_xor(rs, msk);
            l_i[r] = l_i[r] * alpha + rs;
            m_i[r] = mn;
            #pragma unroll
            for (int dt = 0; dt < 8; ++dt) accO[dt][r] *= alpha;
        }
        __syncthreads();               // P visible (also covers cross-wave LDS ordering)
        // O += P V   (A = P[q][s] from Ps, B = V[s][d] via VsT rows)
        short8 pf[2];
        #pragma unroll
        for (int sc = 0; sc < 2; ++sc)
            pf[sc] = *(const short8*)&Ps[w][l16][sc * 32 + quad * 8];
        #pragma unroll
        for (int sc = 0; sc < 2; ++sc) {
            #pragma unroll
            for (int dt = 0; dt < 8; ++dt) {
                short8 vf = *(const short8*)&VsT[dt * 16 + l16][sc * 32 + quad * 8];
                accO[dt] = __builtin_amdgcn_mfma_f32_16x16x32_bf16(pf[sc], vf, accO[dt], 0, 0, 0);
            }
        }
    }
    // epilogue: O[q][d] / l,  q = w*16 + quad*4 + r, d = dt*16 + l16
    float* ob = Om + (size_t)(b * 1024 + q0 + w * 16 + quad * 4) * 2048 + h * 128 + l16;
    #pragma unroll
    for (int r = 0; r < 4; ++r) {
        float inv = 1.f / l_i[r];
        #pragma unroll
        for (int dt = 0; dt < 8; ++dt)
            ob[(size_t)r * 2048 + dt * 16] = accO[dt][r] * inv;
    }
}

extern "C" void kernel_launch(void* const* d_in, const int* in_sizes, int n_in,
                              void* d_out, int out_size, void* d_ws, size_t ws_size,
                              hipStream_t stream)
{
    (void)in_sizes; (void)n_in; (void)out_size; (void)ws_size;
    const float* x_q       = (const float*)d_in[0];
    const float* x_kv      = (const float*)d_in[1];
    const float* W_dQ      = (const float*)d_in[2];
    const float* q_norm_w  = (const float*)d_in[3];
    const float* W_uQ      = (const float*)d_in[4];
    const float* W_dKV     = (const float*)d_in[5];
    const float* kv_norm_w = (const float*)d_in[6];
    const float* W_ukv     = (const float*)d_in[7];
    const float* W_o       = (const float*)d_in[8];
    float* out = (float*)d_out;

    float* ws       = (float*)d_ws;
    float* q_lat    = ws;
    float* q_up     = ws + 1048576ull;
    float* attn_out = ws;                          // region A reuse
    float* ckv      = ws + 7340032ull;
    ushort* kvgb    = (ushort*)(ws + 15728640ull); // 4 x 8192 x 1024 bf16
    ushort* qb      = (ushort*)(ws + 32505856ull); // 2048 x 2048 bf16
    ushort* vt      = (ushort*)(ws + 34603008ull); // 32 x 128 x 4096 bf16

    // 1) q_lat = x_q @ W_dQ
    tgemm<<<dim3(8, 32), 256, 0, stream>>>(x_q, W_dQ, q_lat, 2048, 512, 2048, 2048, 512, 512, 0);
    // 2) rmsnorm
    rms_naive<<<8, 256, 0, stream>>>(q_lat, q_norm_w, 2048, 512, 512, 1);
    // 3) q_up = q_lat @ W_uQ
    tgemm<<<dim3(48, 32), 256, 0, stream>>>(q_lat, W_uQ, q_up, 2048, 3072, 512, 512, 3072, 3072, 0);
    // 3b) per-head [:128] slice -> bf16, scale folded
    extract_q_bf16<<<16384, 256, 0, stream>>>(q_up, qb);
    // 4) ckv = x_kv @ W_dKV[:, :1024]
    tgemm<<<dim3(16, 128), 256, 0, stream>>>(x_kv, W_dKV, ckv, 8192, 1024, 2048, 2048, 1088, 1024, 0);
    // 5) grouped rmsnorm
    rms_naive<<<128, 256, 0, stream>>>(ckv, kv_norm_w, 32768, 256, 1024, 4);
    // 6) kv up-projection per group -> bf16 (ldc in ushorts)
    for (int g = 0; g < 4; ++g)
        tgemm<<<dim3(16, 128), 256, 0, stream>>>(ckv + g * 256, W_ukv + (size_t)g * 262144,
                                                 (float*)(kvgb + (size_t)g * 8388608ull),
                                                 8192, 1024, 256, 1024, 1024, 1024, 1);
    // 6b) V transpose
    transpose_v<<<dim3(64, 2, 32), 256, 0, stream>>>(kvgb, vt);
    // 7) MFMA flash attention
    attn_mfma<<<dim3(16, 16, 2), 256, 0, stream>>>(qb, kvgb, vt, attn_out);
    // 8) out = attn_out @ W_o
    tgemm<<<dim3(32, 32), 256, 0, stream>>>(attn_out, W_o, out, 2048, 2048, 2048, 2048, 2048, 2048, 0);
}

// Round 6
// 779.323 us; speedup vs baseline: 40.2603x; 2.2284x over previous
//
#include <hip/hip_runtime.h>
#include <hip/hip_bf16.h>
#include <math.h>

// GLA cross-attention — round 6: ALL GEMMs on bf16 MFMA (shared gemm_mfma,
// m93-style 128x128/BK=64, fragment layout identical to r5-verified attn).
// Weights pre-transposed+cast to bf16 [N][K]; W_uQ transpose folds the
// per-head [:128] slice (extract kernel deleted); rms emits bf16; attention
// epilogue emits bf16 for the W_o GEMM.
//
// ws layout (float offsets, 199.2 MB total; regions overlap only where
// lifetimes are disjoint — noted per buffer):
//   xkvb   u16 @ 0           (16,777,216 u)  dead after stage 9
//   attn_out_b u16 @ 0        (4,194,304 u)  written stage 14 (aliases xkvb)
//   Wot    u16 @ f4,194,304   (4,194,304 u)  written stage 15 (aliases xkvb)
//   ckv    f32 @ 8,388,608    (8,388,608 f)  written stage 9
//   xqb    u16 @ 8,388,608    (4,194,304 u)  dead after stage 3 (pre-ckv)
//   WdQt   u16 @ 10,485,760   (1,048,576 u)  dead after stage 3
//   q_lat  f32 @ 11,010,048   (1,048,576 f)  dead after stage 4 (rms)
//   q_lat_b u16 @ 12,058,624  (1,048,576 u)  dead after stage 6
//   WuQt   u16 @ 12,582,912   (1,048,576 u)  dead after stage 6
//   ckv_b  u16 @ 16,777,216   (8,388,608 u)
//   kvgb   u16 @ 20,971,520   (33,554,432 u)
//   vt     u16 @ 37,748,736   (16,777,216 u)
//   qb     u16 @ 46,137,344   (4,194,304 u)
//   WdKVt  u16 @ 48,234,496   (2,097,152 u)
//   Wukvt  u16 @ 49,283,072   (1,048,576 u)

typedef __attribute__((ext_vector_type(8))) short short8;
typedef __attribute__((ext_vector_type(4))) float f32x4;

__device__ __forceinline__ ushort f2bf(float x) {
    __hip_bfloat16 h = __float2bfloat16(x);
    return *reinterpret_cast<ushort*>(&h);
}

// ---------- elementwise fp32 -> bf16 cast, 8 elems/thread
__global__ __launch_bounds__(256) void cast_bf16(const float* __restrict__ src,
        ushort* __restrict__ dst)
{
    size_t i = ((size_t)blockIdx.x * 256 + threadIdx.x) * 8;
    float4 a = *(const float4*)(src + i);
    float4 b = *(const float4*)(src + i + 4);
    ushort u[8] = {f2bf(a.x), f2bf(a.y), f2bf(a.z), f2bf(a.w),
                   f2bf(b.x), f2bf(b.y), f2bf(b.z), f2bf(b.w)};
    *(uint4*)(dst + i) = *(uint4*)u;
}

// ---------- transpose + cast: dst[n][k] (bf16, [Ncols][Krows]) = src[k][cb+n]
// grid (K/64, N/64, Z). remap=1 folds W_uQ per-head [:128]-of-192 column map.
__global__ __launch_bounds__(256) void transpose_cast(const float* __restrict__ src,
        ushort* __restrict__ dst, int srl, int dstld, int remap,
        long src_z, long dst_z)
{
    __shared__ ushort tile[64][68];
    const int k0 = blockIdx.x * 64;
    const int n0 = blockIdx.y * 64;
    src += (size_t)blockIdx.z * src_z;
    dst += (size_t)blockIdx.z * dst_z;
    const int cb = n0 + (remap ? (n0 >> 7) * 64 : 0);
    const int t = threadIdx.x;
    {
        int r = t >> 4, c4 = t & 15;
        #pragma unroll
        for (int i = 0; i < 4; ++i) {
            float4 v = *(const float4*)(src + (size_t)(k0 + r + 16 * i) * srl + cb + c4 * 4);
            tile[r + 16 * i][c4 * 4 + 0] = f2bf(v.x);
            tile[r + 16 * i][c4 * 4 + 1] = f2bf(v.y);
            tile[r + 16 * i][c4 * 4 + 2] = f2bf(v.z);
            tile[r + 16 * i][c4 * 4 + 3] = f2bf(v.w);
        }
    }
    __syncthreads();
    {
        int n = t >> 4, k4 = t & 15;
        #pragma unroll
        for (int i = 0; i < 4; ++i) {
            ushort4 v;
            v.x = tile[k4 * 4 + 0][n + 16 * i];
            v.y = tile[k4 * 4 + 1][n + 16 * i];
            v.z = tile[k4 * 4 + 2][n + 16 * i];
            v.w = tile[k4 * 4 + 3][n + 16 * i];
            *(ushort4*)(dst + (size_t)(n0 + n + 16 * i) * dstld + k0 + k4 * 4) = v;
        }
    }
}

// ---------- MFMA bf16 GEMM: C[M,N] = A[M,K] @ Bt[N,K]^T  (both k-contiguous)
// 128x128 tile, BK=64, 4 waves (2x2 of 64x64), 4x4 16x16 accs per wave.
// Fragment scheme identical to r5-verified attn_mfma. obf16 -> bf16 C.
__global__ __launch_bounds__(256) void gemm_mfma(const ushort* __restrict__ A,
        const ushort* __restrict__ Bt, void* __restrict__ Cv,
        int M, int N, int K, int lda, int ldb, int ldc, int obf16, float scale)
{
    __shared__ ushort As[128][72];   // 144B rows: 16B-aligned, 4-bank skew
    __shared__ ushort Bs[128][72];
    const int tid = threadIdx.x;
    const int w = tid >> 6, lane = tid & 63;
    const int quad = lane >> 4, l16 = lane & 15;
    const int wm = (w >> 1) * 64, wn = (w & 1) * 64;
    const int m0 = blockIdx.y * 128, n0 = blockIdx.x * 128;

    f32x4 acc[4][4];
    #pragma unroll
    for (int i = 0; i < 4; ++i)
        #pragma unroll
        for (int j = 0; j < 4; ++j) acc[i][j] = (f32x4){0.f, 0.f, 0.f, 0.f};

    const int str = tid >> 3;            // staging row 0..31 (+32*i)
    const int stc = (tid & 7) * 8;       // staging col (ushorts)

    for (int k0 = 0; k0 < K; k0 += 64) {
        __syncthreads();
        #pragma unroll
        for (int i = 0; i < 4; ++i) {
            int r = str + 32 * i;
            *(uint4*)&As[r][stc] = *(const uint4*)(A + (size_t)(m0 + r) * lda + k0 + stc);
            *(uint4*)&Bs[r][stc] = *(const uint4*)(Bt + (size_t)(n0 + r) * ldb + k0 + stc);
        }
        __syncthreads();
        #pragma unroll
        for (int kc = 0; kc < 2; ++kc) {
            short8 af[4], bf[4];
            #pragma unroll
            for (int i = 0; i < 4; ++i) {
                af[i] = *(const short8*)&As[wm + i * 16 + l16][kc * 32 + quad * 8];
                bf[i] = *(const short8*)&Bs[wn + i * 16 + l16][kc * 32 + quad * 8];
            }
            #pragma unroll
            for (int i = 0; i < 4; ++i)
                #pragma unroll
                for (int j = 0; j < 4; ++j)
                    acc[i][j] = __builtin_amdgcn_mfma_f32_16x16x32_bf16(af[i], bf[j], acc[i][j], 0, 0, 0);
        }
    }
    // C row = m0+wm+i*16+quad*4+r, col = n0+wn+j*16+l16  (verified layout)
    if (!obf16) {
        float* C = (float*)Cv;
        #pragma unroll
        for (int i = 0; i < 4; ++i)
            #pragma unroll
            for (int r = 0; r < 4; ++r) {
                float* cp = C + (size_t)(m0 + wm + i * 16 + quad * 4 + r) * ldc + n0 + wn + l16;
                #pragma unroll
                for (int j = 0; j < 4; ++j) cp[j * 16] = acc[i][j][r] * scale;
            }
    } else {
        ushort* C = (ushort*)Cv;
        #pragma unroll
        for (int i = 0; i < 4; ++i)
            #pragma unroll
            for (int r = 0; r < 4; ++r) {
                ushort* cp = C + (size_t)(m0 + wm + i * 16 + quad * 4 + r) * ldc + n0 + wn + l16;
                #pragma unroll
                for (int j = 0; j < 4; ++j) cp[j * 16] = f2bf(acc[i][j][r] * scale);
            }
    }
}

// ---------- rmsnorm (r3-verified math), bf16 output, fp32 input untouched
__global__ __launch_bounds__(256) void rms_bf16(const float* __restrict__ x,
        const float* __restrict__ w, ushort* __restrict__ dst,
        long n, long cols, long rowstride, long groups)
{
    long t = (long)blockIdx.x * 256 + threadIdx.x;
    if (t >= n) return;
    long r = t / groups, g = t % groups;
    const float* p = x + r * rowstride + g * cols;
    const float* wp = w + g * cols;
    ushort* dp = dst + r * rowstride + g * cols;
    float ss = 0.f;
    for (long c = 0; c < cols; ++c) ss += p[c] * p[c];
    float inv = rsqrtf(ss / (float)cols + 1e-6f);
    for (long c = 0; c < cols; ++c) dp[c] = f2bf(p[c] * inv * wp[c]);
}

// ---------- V transpose (VERIFIED r5): kvgb V-halves -> Vt[b,h][d=128][s=4096]
__global__ __launch_bounds__(256) void transpose_v(const ushort* __restrict__ KVb,
                                                   ushort* __restrict__ Vt)
{
    __shared__ ushort tile[64][66];
    const int s0 = blockIdx.x * 64;
    const int d0 = blockIdx.y * 64;
    const int bh = blockIdx.z;
    const int b = bh >> 4, h = bh & 15, g = h >> 2, p = h & 3;
    const int t = threadIdx.x;
    const ushort* src = KVb + (size_t)g * 8388608ull + (size_t)(b * 4096) * 1024 + p * 256 + 128;
    {
        int sl = t >> 4, c4 = t & 15;
        #pragma unroll
        for (int i = 0; i < 4; ++i) {
            int s = sl + 16 * i;
            ushort4 v = *(const ushort4*)(src + (size_t)(s0 + s) * 1024 + d0 + c4 * 4);
            tile[s][c4 * 4 + 0] = v.x; tile[s][c4 * 4 + 1] = v.y;
            tile[s][c4 * 4 + 2] = v.z; tile[s][c4 * 4 + 3] = v.w;
        }
    }
    __syncthreads();
    {
        int dl = t >> 4, s4 = t & 15;
        ushort* dst = Vt + (size_t)(b * 16 + h) * 128 * 4096;
        #pragma unroll
        for (int i = 0; i < 4; ++i) {
            int d = dl + 16 * i;
            ushort4 v;
            v.x = tile[s4 * 4 + 0][d]; v.y = tile[s4 * 4 + 1][d];
            v.z = tile[s4 * 4 + 2][d]; v.w = tile[s4 * 4 + 3][d];
            *(ushort4*)(dst + (size_t)(d0 + d) * 4096 + s0 + s4 * 4) = v;
        }
    }
}

// ---------- MFMA bf16 flash attention (VERIFIED r5; epilogue now bf16)
__global__ __launch_bounds__(256) void attn_mfma(const ushort* __restrict__ Qb,
        const ushort* __restrict__ KVb, const ushort* __restrict__ Vt,
        ushort* __restrict__ Om)
{
    __shared__ ushort Ks[64][136];
    __shared__ ushort VsT[128][72];
    __shared__ ushort Ps[4][16][72];

    const int q0 = blockIdx.x * 64;
    const int h = blockIdx.y, b = blockIdx.z;
    const int g = h >> 2, p = h & 3;
    const int tid = threadIdx.x;
    const int w = tid >> 6, lane = tid & 63;
    const int quad = lane >> 4, l16 = lane & 15;

    const ushort* qg = Qb + (size_t)(b * 1024 + q0) * 2048 + h * 128;
    const ushort* kg = KVb + (size_t)g * 8388608ull + (size_t)(b * 4096) * 1024 + p * 256;
    const ushort* vg = Vt + (size_t)(b * 16 + h) * 128 * 4096;

    {
        int r = tid >> 4, c8 = tid & 15;
        #pragma unroll
        for (int i = 0; i < 4; ++i)
            *(uint4*)&Ks[r + 16 * i][c8 * 8] =
                *(const uint4*)(qg + (size_t)(r + 16 * i) * 2048 + c8 * 8);
    }
    __syncthreads();
    short8 qf[4];
    {
        int qr = w * 16 + l16;
        #pragma unroll
        for (int kc = 0; kc < 4; ++kc)
            qf[kc] = *(const short8*)&Ks[qr][kc * 32 + quad * 8];
    }

    f32x4 accO[8];
    float m_i[4], l_i[4];
    #pragma unroll
    for (int dt = 0; dt < 8; ++dt) accO[dt] = (f32x4){0.f, 0.f, 0.f, 0.f};
    #pragma unroll
    for (int r = 0; r < 4; ++r) { m_i[r] = -INFINITY; l_i[r] = 0.f; }

    for (int s0 = 0; s0 < 4096; s0 += 64) {
        __syncthreads();
        {
            int r = tid >> 4, c8 = tid & 15;
            #pragma unroll
            for (int i = 0; i < 4; ++i)
                *(uint4*)&Ks[r + 16 * i][c8 * 8] =
                    *(const uint4*)(kg + (size_t)(s0 + r + 16 * i) * 1024 + c8 * 8);
            int d = tid >> 3, s8 = tid & 7;
            #pragma unroll
            for (int i = 0; i < 4; ++i)
                *(uint4*)&VsT[d + 32 * i][s8 * 8] =
                    *(const uint4*)(vg + (size_t)(d + 32 * i) * 4096 + s0 + s8 * 8);
        }
        __syncthreads();
        f32x4 accS[4];
        #pragma unroll
        for (int st = 0; st < 4; ++st) accS[st] = (f32x4){0.f, 0.f, 0.f, 0.f};
        #pragma unroll
        for (int kc = 0; kc < 4; ++kc) {
            #pragma unroll
            for (int st = 0; st < 4; ++st) {
                short8 kf = *(const short8*)&Ks[st * 16 + l16][kc * 32 + quad * 8];
                accS[st] = __builtin_amdgcn_mfma_f32_16x16x32_bf16(qf[kc], kf, accS[st], 0, 0, 0);
            }
        }
        #pragma unroll
        for (int r = 0; r < 4; ++r) {
            float tm = fmaxf(fmaxf(accS[0][r], accS[1][r]), fmaxf(accS[2][r], accS[3][r]));
            #pragma unroll
            for (int msk = 1; msk < 16; msk <<= 1) tm = fmaxf(tm, __shfl_xor(tm, msk));
            float mn = fmaxf(m_i[r], tm);
            float alpha = __expf(m_i[r] - mn);
            float rs = 0.f;
            #pragma unroll
            for (int st = 0; st < 4; ++st) {
                float e = __expf(accS[st][r] - mn);
                rs += e;
                Ps[w][quad * 4 + r][st * 16 + l16] = f2bf(e);
            }
            #pragma unroll
            for (int msk = 1; msk < 16; msk <<= 1) rs += __shfl_xor(rs, msk);
            l_i[r] = l_i[r] * alpha + rs;
            m_i[r] = mn;
            #pragma unroll
            for (int dt = 0; dt < 8; ++dt) accO[dt][r] *= alpha;
        }
        __syncthreads();
        short8 pf[2];
        #pragma unroll
        for (int sc = 0; sc < 2; ++sc)
            pf[sc] = *(const short8*)&Ps[w][l16][sc * 32 + quad * 8];
        #pragma unroll
        for (int sc = 0; sc < 2; ++sc) {
            #pragma unroll
            for (int dt = 0; dt < 8; ++dt) {
                short8 vf = *(const short8*)&VsT[dt * 16 + l16][sc * 32 + quad * 8];
                accO[dt] = __builtin_amdgcn_mfma_f32_16x16x32_bf16(pf[sc], vf, accO[dt], 0, 0, 0);
            }
        }
    }
    ushort* ob = Om + (size_t)(b * 1024 + q0 + w * 16 + quad * 4) * 2048 + h * 128 + l16;
    #pragma unroll
    for (int r = 0; r < 4; ++r) {
        float inv = 1.f / l_i[r];
        #pragma unroll
        for (int dt = 0; dt < 8; ++dt)
            ob[(size_t)r * 2048 + dt * 16] = f2bf(accO[dt][r] * inv);
    }
}

extern "C" void kernel_launch(void* const* d_in, const int* in_sizes, int n_in,
                              void* d_out, int out_size, void* d_ws, size_t ws_size,
                              hipStream_t stream)
{
    (void)in_sizes; (void)n_in; (void)out_size; (void)ws_size;
    const float* x_q       = (const float*)d_in[0];
    const float* x_kv      = (const float*)d_in[1];
    const float* W_dQ      = (const float*)d_in[2];
    const float* q_norm_w  = (const float*)d_in[3];
    const float* W_uQ      = (const float*)d_in[4];
    const float* W_dKV     = (const float*)d_in[5];
    const float* kv_norm_w = (const float*)d_in[6];
    const float* W_ukv     = (const float*)d_in[7];
    const float* W_o       = (const float*)d_in[8];
    float* out = (float*)d_out;

    float* ws = (float*)d_ws;
    ushort* xkvb       = (ushort*)ws;                     // dead after st9
    ushort* attn_out_b = (ushort*)ws;                     // st14+ (aliases xkvb)
    ushort* Wot        = (ushort*)(ws + 4194304ull);      // st15+ (aliases xkvb)
    float*  ckv        = ws + 8388608ull;                 // st9+
    ushort* xqb        = (ushort*)(ws + 8388608ull);      // st1-3 (pre-ckv)
    ushort* WdQt       = (ushort*)(ws + 10485760ull);
    float*  q_lat      = ws + 11010048ull;
    ushort* q_lat_b    = (ushort*)(ws + 12058624ull);
    ushort* WuQt       = (ushort*)(ws + 12582912ull);
    ushort* ckv_b      = (ushort*)(ws + 16777216ull);
    ushort* kvgb       = (ushort*)(ws + 20971520ull);
    ushort* vt         = (ushort*)(ws + 37748736ull);
    ushort* qb         = (ushort*)(ws + 46137344ull);
    ushort* WdKVt      = (ushort*)(ws + 48234496ull);
    ushort* Wukvt      = (ushort*)(ws + 49283072ull);

    const float qscale = 0.08838834764831845f;            // 1/sqrt(128)

    // 1-3) q_lat = bf16(x_q) @ bf16(W_dQ)
    cast_bf16<<<2048, 256, 0, stream>>>(x_q, xqb);
    transpose_cast<<<dim3(32, 8, 1), 256, 0, stream>>>(W_dQ, WdQt, 512, 2048, 0, 0, 0);
    gemm_mfma<<<dim3(4, 16), 256, 0, stream>>>(xqb, WdQt, q_lat, 2048, 512, 2048, 2048, 2048, 512, 0, 1.f);
    // 4) rmsnorm -> bf16
    rms_bf16<<<8, 256, 0, stream>>>(q_lat, q_norm_w, q_lat_b, 2048, 512, 512, 1);
    // 5-6) qb = (q_lat_b @ W_uQ[:, head :128 slice]) * qscale, bf16
    transpose_cast<<<dim3(8, 32, 1), 256, 0, stream>>>(W_uQ, WuQt, 3072, 512, 1, 0, 0);
    gemm_mfma<<<dim3(16, 16), 256, 0, stream>>>(q_lat_b, WuQt, qb, 2048, 2048, 512, 512, 512, 2048, 1, qscale);
    // 7-9) ckv = bf16(x_kv) @ bf16(W_dKV[:, :1024])
    cast_bf16<<<8192, 256, 0, stream>>>(x_kv, xkvb);
    transpose_cast<<<dim3(32, 16, 1), 256, 0, stream>>>(W_dKV, WdKVt, 1088, 2048, 0, 0, 0);
    gemm_mfma<<<dim3(8, 64), 256, 0, stream>>>(xkvb, WdKVt, ckv, 8192, 1024, 2048, 2048, 2048, 1024, 0, 1.f);
    // 10) grouped rmsnorm -> bf16
    rms_bf16<<<128, 256, 0, stream>>>(ckv, kv_norm_w, ckv_b, 32768, 256, 1024, 4);
    // 11-12) kv up-projection per group -> bf16 kvgb
    transpose_cast<<<dim3(4, 16, 4), 256, 0, stream>>>(W_ukv, Wukvt, 1024, 256, 0, 262144, 262144);
    for (int g = 0; g < 4; ++g)
        gemm_mfma<<<dim3(8, 64), 256, 0, stream>>>(ckv_b + g * 256, Wukvt + (size_t)g * 262144,
                                                   kvgb + (size_t)g * 8388608ull,
                                                   8192, 1024, 256, 1024, 256, 1024, 1, 1.f);
    // 13) V transpose
    transpose_v<<<dim3(64, 2, 32), 256, 0, stream>>>(kvgb, vt);
    // 14) MFMA flash attention -> bf16
    attn_mfma<<<dim3(16, 16, 2), 256, 0, stream>>>(qb, kvgb, vt, attn_out_b);
    // 15-16) out = attn_out_b @ bf16(W_o)
    transpose_cast<<<dim3(32, 32, 1), 256, 0, stream>>>(W_o, Wot, 2048, 2048, 0, 0, 0);
    gemm_mfma<<<dim3(16, 16), 256, 0, stream>>>(attn_out_b, Wot, out, 2048, 2048, 2048, 2048, 2048, 2048, 0, 1.f);
}

// Round 7
// 555.498 us; speedup vs baseline: 56.4822x; 1.4029x over previous
//
#include <hip/hip_runtime.h>
#include <hip/hip_bf16.h>
#include <math.h>

// GLA cross-attention — round 7:
//  (a) split-s flash attention (SPLIT=2): 2x occupancy; fp32 partials (O,m,l)
//      into the dead ckv region; exact merge kernel.
//  (b) coalesced wave-per-row rmsnorm (replaces thread-per-row scalar loops,
//      which were ~16x overfetching and likely ~300 us of round 6).
// Everything else byte-identical to the PASSING round 6.
//
// ws float-offset map (alias notes; top = 49,807,360 f = 199.2 MB):
//   attn_out_b u16 @ 0          (4,194,304 u -> 2,097,152 f)
//   ml        f32 @ 2,097,152   (131,072 f)   [attn stage only; gap before Wot]
//   Wot       u16 @ f4,194,304  (4,194,304 u) [stage 15+]
//   xkvb      u16 @ 0           dead after stage 9 (aliases the above, disjoint in time)
//   ckv       f32 @ 8,388,608   (8,388,608 f) dead after stage 10
//   Opart     f32 @ 8,388,608   (8,388,608 f) [attn stage; aliases dead ckv]
//   xqb/WdQt/q_lat/q_lat_b/WuQt in 8,388,608..13,631,488 (all dead pre-stage-9)
//   ckv_b u16 @ 16,777,216 | kvgb u16 @ 20,971,520 | vt u16 @ 37,748,736
//   qb u16 @ 46,137,344 | WdKVt u16 @ 48,234,496 | Wukvt u16 @ 49,283,072

typedef __attribute__((ext_vector_type(8))) short short8;
typedef __attribute__((ext_vector_type(4))) float f32x4;

__device__ __forceinline__ ushort f2bf(float x) {
    __hip_bfloat16 h = __float2bfloat16(x);
    return *reinterpret_cast<ushort*>(&h);
}

// ---------- elementwise fp32 -> bf16 cast, 8 elems/thread (VERIFIED r6)
__global__ __launch_bounds__(256) void cast_bf16(const float* __restrict__ src,
        ushort* __restrict__ dst)
{
    size_t i = ((size_t)blockIdx.x * 256 + threadIdx.x) * 8;
    float4 a = *(const float4*)(src + i);
    float4 b = *(const float4*)(src + i + 4);
    ushort u[8] = {f2bf(a.x), f2bf(a.y), f2bf(a.z), f2bf(a.w),
                   f2bf(b.x), f2bf(b.y), f2bf(b.z), f2bf(b.w)};
    *(uint4*)(dst + i) = *(uint4*)u;
}

// ---------- transpose + cast (VERIFIED r6)
__global__ __launch_bounds__(256) void transpose_cast(const float* __restrict__ src,
        ushort* __restrict__ dst, int srl, int dstld, int remap,
        long src_z, long dst_z)
{
    __shared__ ushort tile[64][68];
    const int k0 = blockIdx.x * 64;
    const int n0 = blockIdx.y * 64;
    src += (size_t)blockIdx.z * src_z;
    dst += (size_t)blockIdx.z * dst_z;
    const int cb = n0 + (remap ? (n0 >> 7) * 64 : 0);
    const int t = threadIdx.x;
    {
        int r = t >> 4, c4 = t & 15;
        #pragma unroll
        for (int i = 0; i < 4; ++i) {
            float4 v = *(const float4*)(src + (size_t)(k0 + r + 16 * i) * srl + cb + c4 * 4);
            tile[r + 16 * i][c4 * 4 + 0] = f2bf(v.x);
            tile[r + 16 * i][c4 * 4 + 1] = f2bf(v.y);
            tile[r + 16 * i][c4 * 4 + 2] = f2bf(v.z);
            tile[r + 16 * i][c4 * 4 + 3] = f2bf(v.w);
        }
    }
    __syncthreads();
    {
        int n = t >> 4, k4 = t & 15;
        #pragma unroll
        for (int i = 0; i < 4; ++i) {
            ushort4 v;
            v.x = tile[k4 * 4 + 0][n + 16 * i];
            v.y = tile[k4 * 4 + 1][n + 16 * i];
            v.z = tile[k4 * 4 + 2][n + 16 * i];
            v.w = tile[k4 * 4 + 3][n + 16 * i];
            *(ushort4*)(dst + (size_t)(n0 + n + 16 * i) * dstld + k0 + k4 * 4) = v;
        }
    }
}

// ---------- MFMA bf16 GEMM (VERIFIED r6)
__global__ __launch_bounds__(256) void gemm_mfma(const ushort* __restrict__ A,
        const ushort* __restrict__ Bt, void* __restrict__ Cv,
        int M, int N, int K, int lda, int ldb, int ldc, int obf16, float scale)
{
    __shared__ ushort As[128][72];
    __shared__ ushort Bs[128][72];
    const int tid = threadIdx.x;
    const int w = tid >> 6, lane = tid & 63;
    const int quad = lane >> 4, l16 = lane & 15;
    const int wm = (w >> 1) * 64, wn = (w & 1) * 64;
    const int m0 = blockIdx.y * 128, n0 = blockIdx.x * 128;

    f32x4 acc[4][4];
    #pragma unroll
    for (int i = 0; i < 4; ++i)
        #pragma unroll
        for (int j = 0; j < 4; ++j) acc[i][j] = (f32x4){0.f, 0.f, 0.f, 0.f};

    const int str = tid >> 3;
    const int stc = (tid & 7) * 8;

    for (int k0 = 0; k0 < K; k0 += 64) {
        __syncthreads();
        #pragma unroll
        for (int i = 0; i < 4; ++i) {
            int r = str + 32 * i;
            *(uint4*)&As[r][stc] = *(const uint4*)(A + (size_t)(m0 + r) * lda + k0 + stc);
            *(uint4*)&Bs[r][stc] = *(const uint4*)(Bt + (size_t)(n0 + r) * ldb + k0 + stc);
        }
        __syncthreads();
        #pragma unroll
        for (int kc = 0; kc < 2; ++kc) {
            short8 af[4], bf[4];
            #pragma unroll
            for (int i = 0; i < 4; ++i) {
                af[i] = *(const short8*)&As[wm + i * 16 + l16][kc * 32 + quad * 8];
                bf[i] = *(const short8*)&Bs[wn + i * 16 + l16][kc * 32 + quad * 8];
            }
            #pragma unroll
            for (int i = 0; i < 4; ++i)
                #pragma unroll
                for (int j = 0; j < 4; ++j)
                    acc[i][j] = __builtin_amdgcn_mfma_f32_16x16x32_bf16(af[i], bf[j], acc[i][j], 0, 0, 0);
        }
    }
    if (!obf16) {
        float* C = (float*)Cv;
        #pragma unroll
        for (int i = 0; i < 4; ++i)
            #pragma unroll
            for (int r = 0; r < 4; ++r) {
                float* cp = C + (size_t)(m0 + wm + i * 16 + quad * 4 + r) * ldc + n0 + wn + l16;
                #pragma unroll
                for (int j = 0; j < 4; ++j) cp[j * 16] = acc[i][j][r] * scale;
            }
    } else {
        ushort* C = (ushort*)Cv;
        #pragma unroll
        for (int i = 0; i < 4; ++i)
            #pragma unroll
            for (int r = 0; r < 4; ++r) {
                ushort* cp = C + (size_t)(m0 + wm + i * 16 + quad * 4 + r) * ldc + n0 + wn + l16;
                #pragma unroll
                for (int j = 0; j < 4; ++j) cp[j * 16] = f2bf(acc[i][j][r] * scale);
            }
    }
}

// ---------- NEW coalesced rmsnorm, 512 cols, wave per row, bf16 out
__global__ __launch_bounds__(256) void rms_q_wave(const float* __restrict__ x,
        const float* __restrict__ w, ushort* __restrict__ dst)
{
    const int row = blockIdx.x * 4 + (threadIdx.x >> 6);
    const int lane = threadIdx.x & 63;
    const float* p = x + (size_t)row * 512;
    float4 v0 = *(const float4*)(p + lane * 4);
    float4 v1 = *(const float4*)(p + 256 + lane * 4);
    float ss = v0.x*v0.x + v0.y*v0.y + v0.z*v0.z + v0.w*v0.w
             + v1.x*v1.x + v1.y*v1.y + v1.z*v1.z + v1.w*v1.w;
    #pragma unroll
    for (int m = 1; m < 64; m <<= 1) ss += __shfl_xor(ss, m);
    float inv = rsqrtf(ss * (1.f / 512.f) + 1e-6f);
    float4 w0 = *(const float4*)(w + lane * 4);
    float4 w1 = *(const float4*)(w + 256 + lane * 4);
    ushort* dp = dst + (size_t)row * 512;
    ushort4 o0, o1;
    o0.x = f2bf(v0.x * inv * w0.x); o0.y = f2bf(v0.y * inv * w0.y);
    o0.z = f2bf(v0.z * inv * w0.z); o0.w = f2bf(v0.w * inv * w0.w);
    o1.x = f2bf(v1.x * inv * w1.x); o1.y = f2bf(v1.y * inv * w1.y);
    o1.z = f2bf(v1.z * inv * w1.z); o1.w = f2bf(v1.w * inv * w1.w);
    *(ushort4*)(dp + lane * 4)       = o0;
    *(ushort4*)(dp + 256 + lane * 4) = o1;
}

// ---------- NEW coalesced grouped rmsnorm, 256 cols/group, wave per (row,g)
__global__ __launch_bounds__(256) void rms_kv_wave(const float* __restrict__ x,
        const float* __restrict__ w, ushort* __restrict__ dst)
{
    const int idx = blockIdx.x * 4 + (threadIdx.x >> 6);   // 0..32767
    const int lane = threadIdx.x & 63;
    const int r = idx >> 2, g = idx & 3;
    const float* p = x + (size_t)r * 1024 + g * 256;
    float4 v = *(const float4*)(p + lane * 4);
    float ss = v.x*v.x + v.y*v.y + v.z*v.z + v.w*v.w;
    #pragma unroll
    for (int m = 1; m < 64; m <<= 1) ss += __shfl_xor(ss, m);
    float inv = rsqrtf(ss * (1.f / 256.f) + 1e-6f);
    float4 wv = *(const float4*)(w + g * 256 + lane * 4);
    ushort4 o;
    o.x = f2bf(v.x * inv * wv.x); o.y = f2bf(v.y * inv * wv.y);
    o.z = f2bf(v.z * inv * wv.z); o.w = f2bf(v.w * inv * wv.w);
    *(ushort4*)(dst + (size_t)r * 1024 + g * 256 + lane * 4) = o;
}

// ---------- V transpose (VERIFIED r5/r6)
__global__ __launch_bounds__(256) void transpose_v(const ushort* __restrict__ KVb,
                                                   ushort* __restrict__ Vt)
{
    __shared__ ushort tile[64][66];
    const int s0 = blockIdx.x * 64;
    const int d0 = blockIdx.y * 64;
    const int bh = blockIdx.z;
    const int b = bh >> 4, h = bh & 15, g = h >> 2, p = h & 3;
    const int t = threadIdx.x;
    const ushort* src = KVb + (size_t)g * 8388608ull + (size_t)(b * 4096) * 1024 + p * 256 + 128;
    {
        int sl = t >> 4, c4 = t & 15;
        #pragma unroll
        for (int i = 0; i < 4; ++i) {
            int s = sl + 16 * i;
            ushort4 v = *(const ushort4*)(src + (size_t)(s0 + s) * 1024 + d0 + c4 * 4);
            tile[s][c4 * 4 + 0] = v.x; tile[s][c4 * 4 + 1] = v.y;
            tile[s][c4 * 4 + 2] = v.z; tile[s][c4 * 4 + 3] = v.w;
        }
    }
    __syncthreads();
    {
        int dl = t >> 4, s4 = t & 15;
        ushort* dst = Vt + (size_t)(b * 16 + h) * 128 * 4096;
        #pragma unroll
        for (int i = 0; i < 4; ++i) {
            int d = dl + 16 * i;
            ushort4 v;
            v.x = tile[s4 * 4 + 0][d]; v.y = tile[s4 * 4 + 1][d];
            v.z = tile[s4 * 4 + 2][d]; v.w = tile[s4 * 4 + 3][d];
            *(ushort4*)(dst + (size_t)(d0 + d) * 4096 + s0 + s4 * 4) = v;
        }
    }
}

// ---------- MFMA flash attention, SPLIT-s=2 (r5/r6-verified core).
// grid (16, 16, 4): z = b*2 + chunk; chunk covers s in [chunk*2048, +2048).
// Writes UNNORMALIZED fp32 O partials + per-row (m,l) for the merge pass.
__global__ __launch_bounds__(256) void attn_mfma_split(const ushort* __restrict__ Qb,
        const ushort* __restrict__ KVb, const ushort* __restrict__ Vt,
        float* __restrict__ Opart, float* __restrict__ ml)
{
    __shared__ ushort Ks[64][136];
    __shared__ ushort VsT[128][72];
    __shared__ ushort Ps[4][16][72];

    const int q0 = blockIdx.x * 64;
    const int h = blockIdx.y;
    const int b = blockIdx.z >> 1, chunk = blockIdx.z & 1;
    const int g = h >> 2, p = h & 3;
    const int tid = threadIdx.x;
    const int w = tid >> 6, lane = tid & 63;
    const int quad = lane >> 4, l16 = lane & 15;
    const int sbase = chunk * 2048;

    const ushort* qg = Qb + (size_t)(b * 1024 + q0) * 2048 + h * 128;
    const ushort* kg = KVb + (size_t)g * 8388608ull + (size_t)(b * 4096 + sbase) * 1024 + p * 256;
    const ushort* vg = Vt + (size_t)(b * 16 + h) * 128 * 4096 + sbase;

    {
        int r = tid >> 4, c8 = tid & 15;
        #pragma unroll
        for (int i = 0; i < 4; ++i)
            *(uint4*)&Ks[r + 16 * i][c8 * 8] =
                *(const uint4*)(qg + (size_t)(r + 16 * i) * 2048 + c8 * 8);
    }
    __syncthreads();
    short8 qf[4];
    {
        int qr = w * 16 + l16;
        #pragma unroll
        for (int kc = 0; kc < 4; ++kc)
            qf[kc] = *(const short8*)&Ks[qr][kc * 32 + quad * 8];
    }

    f32x4 accO[8];
    float m_i[4], l_i[4];
    #pragma unroll
    for (int dt = 0; dt < 8; ++dt) accO[dt] = (f32x4){0.f, 0.f, 0.f, 0.f};
    #pragma unroll
    for (int r = 0; r < 4; ++r) { m_i[r] = -INFINITY; l_i[r] = 0.f; }

    for (int s0 = 0; s0 < 2048; s0 += 64) {
        __syncthreads();
        {
            int r = tid >> 4, c8 = tid & 15;
            #pragma unroll
            for (int i = 0; i < 4; ++i)
                *(uint4*)&Ks[r + 16 * i][c8 * 8] =
                    *(const uint4*)(kg + (size_t)(s0 + r + 16 * i) * 1024 + c8 * 8);
            int d = tid >> 3, s8 = tid & 7;
            #pragma unroll
            for (int i = 0; i < 4; ++i)
                *(uint4*)&VsT[d + 32 * i][s8 * 8] =
                    *(const uint4*)(vg + (size_t)(d + 32 * i) * 4096 + s0 + s8 * 8);
        }
        __syncthreads();
        f32x4 accS[4];
        #pragma unroll
        for (int st = 0; st < 4; ++st) accS[st] = (f32x4){0.f, 0.f, 0.f, 0.f};
        #pragma unroll
        for (int kc = 0; kc < 4; ++kc) {
            #pragma unroll
            for (int st = 0; st < 4; ++st) {
                short8 kf = *(const short8*)&Ks[st * 16 + l16][kc * 32 + quad * 8];
                accS[st] = __builtin_amdgcn_mfma_f32_16x16x32_bf16(qf[kc], kf, accS[st], 0, 0, 0);
            }
        }
        #pragma unroll
        for (int r = 0; r < 4; ++r) {
            float tm = fmaxf(fmaxf(accS[0][r], accS[1][r]), fmaxf(accS[2][r], accS[3][r]));
            #pragma unroll
            for (int msk = 1; msk < 16; msk <<= 1) tm = fmaxf(tm, __shfl_xor(tm, msk));
            float mn = fmaxf(m_i[r], tm);
            float alpha = __expf(m_i[r] - mn);
            float rs = 0.f;
            #pragma unroll
            for (int st = 0; st < 4; ++st) {
                float e = __expf(accS[st][r] - mn);
                rs += e;
                Ps[w][quad * 4 + r][st * 16 + l16] = f2bf(e);
            }
            #pragma unroll
            for (int msk = 1; msk < 16; msk <<= 1) rs += __shfl_xor(rs, msk);
            l_i[r] = l_i[r] * alpha + rs;
            m_i[r] = mn;
            #pragma unroll
            for (int dt = 0; dt < 8; ++dt) accO[dt][r] *= alpha;
        }
        __syncthreads();
        short8 pf[2];
        #pragma unroll
        for (int sc = 0; sc < 2; ++sc)
            pf[sc] = *(const short8*)&Ps[w][l16][sc * 32 + quad * 8];
        #pragma unroll
        for (int sc = 0; sc < 2; ++sc) {
            #pragma unroll
            for (int dt = 0; dt < 8; ++dt) {
                short8 vf = *(const short8*)&VsT[dt * 16 + l16][sc * 32 + quad * 8];
                accO[dt] = __builtin_amdgcn_mfma_f32_16x16x32_bf16(pf[sc], vf, accO[dt], 0, 0, 0);
            }
        }
    }
    // epilogue: unnormalized fp32 partials + (m,l)
    const int qrow = q0 + w * 16 + quad * 4;
    float* ob = Opart + (size_t)((chunk * 2 + b) * 1024 + qrow) * 2048 + h * 128 + l16;
    #pragma unroll
    for (int r = 0; r < 4; ++r)
        #pragma unroll
        for (int dt = 0; dt < 8; ++dt)
            ob[(size_t)r * 2048 + dt * 16] = accO[dt][r];
    if (l16 == 0) {
        #pragma unroll
        for (int r = 0; r < 4; ++r) {
            size_t mi = ((size_t)((chunk * 2 + b) * 1024 + qrow + r) * 16 + h) * 2;
            ml[mi] = m_i[r];
            ml[mi + 1] = l_i[r];
        }
    }
}

// ---------- merge the 2 s-chunks: one wave per (b,q,h); lane owns d=lane, lane+64
__global__ __launch_bounds__(256) void attn_merge(const float* __restrict__ Opart,
        const float* __restrict__ ml, ushort* __restrict__ Om)
{
    const int idx = blockIdx.x * 4 + (threadIdx.x >> 6);  // 0..32767
    const int lane = threadIdx.x & 63;
    const int h = idx & 15;
    const int q = (idx >> 4) & 1023;
    const int b = idx >> 14;

    size_t m1i = ((size_t)((0 * 2 + b) * 1024 + q) * 16 + h) * 2;
    size_t m2i = ((size_t)((1 * 2 + b) * 1024 + q) * 16 + h) * 2;
    float m1 = ml[m1i], l1 = ml[m1i + 1];
    float m2 = ml[m2i], l2 = ml[m2i + 1];
    float M = fmaxf(m1, m2);
    float w1 = __expf(m1 - M), w2 = __expf(m2 - M);
    float invL = 1.f / (l1 * w1 + l2 * w2);

    const float* o1 = Opart + (size_t)((0 * 2 + b) * 1024 + q) * 2048 + h * 128;
    const float* o2 = Opart + (size_t)((1 * 2 + b) * 1024 + q) * 2048 + h * 128;
    ushort* ob = Om + (size_t)(b * 1024 + q) * 2048 + h * 128;
    ob[lane]      = f2bf((o1[lane]      * w1 + o2[lane]      * w2) * invL);
    ob[lane + 64] = f2bf((o1[lane + 64] * w1 + o2[lane + 64] * w2) * invL);
}

extern "C" void kernel_launch(void* const* d_in, const int* in_sizes, int n_in,
                              void* d_out, int out_size, void* d_ws, size_t ws_size,
                              hipStream_t stream)
{
    (void)in_sizes; (void)n_in; (void)out_size; (void)ws_size;
    const float* x_q       = (const float*)d_in[0];
    const float* x_kv      = (const float*)d_in[1];
    const float* W_dQ      = (const float*)d_in[2];
    const float* q_norm_w  = (const float*)d_in[3];
    const float* W_uQ      = (const float*)d_in[4];
    const float* W_dKV     = (const float*)d_in[5];
    const float* kv_norm_w = (const float*)d_in[6];
    const float* W_ukv     = (const float*)d_in[7];
    const float* W_o       = (const float*)d_in[8];
    float* out = (float*)d_out;

    float* ws = (float*)d_ws;
    ushort* xkvb       = (ushort*)ws;
    ushort* attn_out_b = (ushort*)ws;
    float*  mlbuf      = ws + 2097152ull;
    ushort* Wot        = (ushort*)(ws + 4194304ull);
    float*  ckv        = ws + 8388608ull;
    float*  Opart      = ws + 8388608ull;                 // aliases dead ckv
    ushort* xqb        = (ushort*)(ws + 8388608ull);      // pre-stage-9 only
    ushort* WdQt       = (ushort*)(ws + 10485760ull);
    float*  q_lat      = ws + 11010048ull;
    ushort* q_lat_b    = (ushort*)(ws + 12058624ull);
    ushort* WuQt       = (ushort*)(ws + 12582912ull);
    ushort* ckv_b      = (ushort*)(ws + 16777216ull);
    ushort* kvgb       = (ushort*)(ws + 20971520ull);
    ushort* vt         = (ushort*)(ws + 37748736ull);
    ushort* qb         = (ushort*)(ws + 46137344ull);
    ushort* WdKVt      = (ushort*)(ws + 48234496ull);
    ushort* Wukvt      = (ushort*)(ws + 49283072ull);

    const float qscale = 0.08838834764831845f;            // 1/sqrt(128)

    // 1-3) q_lat = bf16(x_q) @ bf16(W_dQ)
    cast_bf16<<<2048, 256, 0, stream>>>(x_q, xqb);
    transpose_cast<<<dim3(32, 8, 1), 256, 0, stream>>>(W_dQ, WdQt, 512, 2048, 0, 0, 0);
    gemm_mfma<<<dim3(4, 16), 256, 0, stream>>>(xqb, WdQt, q_lat, 2048, 512, 2048, 2048, 2048, 512, 0, 1.f);
    // 4) rmsnorm -> bf16 (coalesced)
    rms_q_wave<<<512, 256, 0, stream>>>(q_lat, q_norm_w, q_lat_b);
    // 5-6) qb = (q_lat_b @ W_uQ[:, head :128]) * qscale
    transpose_cast<<<dim3(8, 32, 1), 256, 0, stream>>>(W_uQ, WuQt, 3072, 512, 1, 0, 0);
    gemm_mfma<<<dim3(16, 16), 256, 0, stream>>>(q_lat_b, WuQt, qb, 2048, 2048, 512, 512, 512, 2048, 1, qscale);
    // 7-9) ckv = bf16(x_kv) @ bf16(W_dKV[:, :1024])
    cast_bf16<<<8192, 256, 0, stream>>>(x_kv, xkvb);
    transpose_cast<<<dim3(32, 16, 1), 256, 0, stream>>>(W_dKV, WdKVt, 1088, 2048, 0, 0, 0);
    gemm_mfma<<<dim3(8, 64), 256, 0, stream>>>(xkvb, WdKVt, ckv, 8192, 1024, 2048, 2048, 2048, 1024, 0, 1.f);
    // 10) grouped rmsnorm -> bf16 (coalesced)
    rms_kv_wave<<<8192, 256, 0, stream>>>(ckv, kv_norm_w, ckv_b);
    // 11-12) kv up-projection per group -> bf16 kvgb
    transpose_cast<<<dim3(4, 16, 4), 256, 0, stream>>>(W_ukv, Wukvt, 1024, 256, 0, 262144, 262144);
    for (int g = 0; g < 4; ++g)
        gemm_mfma<<<dim3(8, 64), 256, 0, stream>>>(ckv_b + g * 256, Wukvt + (size_t)g * 262144,
                                                   kvgb + (size_t)g * 8388608ull,
                                                   8192, 1024, 256, 1024, 256, 1024, 1, 1.f);
    // 13) V transpose
    transpose_v<<<dim3(64, 2, 32), 256, 0, stream>>>(kvgb, vt);
    // 14) split-s MFMA flash attention + merge
    attn_mfma_split<<<dim3(16, 16, 4), 256, 0, stream>>>(qb, kvgb, vt, Opart, mlbuf);
    attn_merge<<<8192, 256, 0, stream>>>(Opart, mlbuf, attn_out_b);
    // 15-16) out = attn_out_b @ bf16(W_o)
    transpose_cast<<<dim3(32, 32, 1), 256, 0, stream>>>(W_o, Wot, 2048, 2048, 0, 0, 0);
    gemm_mfma<<<dim3(16, 16), 256, 0, stream>>>(attn_out_b, Wot, out, 2048, 2048, 2048, 2048, 2048, 2048, 0, 1.f);
}